// Round 5
// baseline (859.454 us; speedup 1.0000x reference)
//
#include <hip/hip_runtime.h>
#include <hip/hip_fp16.h>
#include <math.h>

#define N_NODES 50000
#define E_EDGES 1600000
#define TAU     0.5f
#define BN_EPS  1e-5f

__device__ __forceinline__ float dot8h(int4 a, int4 b) {
  const __half2* ah = (const __half2*)&a;
  const __half2* bh = (const __half2*)&b;
  float acc = 0.0f;
  #pragma unroll
  for (int q = 0; q < 4; ++q) {
    float2 fa = __half22float2(ah[q]);
    float2 fb = __half22float2(bh[q]);
    acc = fmaf(fa.x, fb.x, acc);
    acc = fmaf(fa.y, fb.y, acc);
  }
  return acc;
}

// ---------------------------------------------------------------------------
// 1) normalized fp16 features: xn[i] = fp16( x_i / (||x_i|| + 1e-12) )
__global__ __launch_bounds__(256) void xn_norm(
    const float* __restrict__ x, __half* __restrict__ xn, int n) {
  int wid  = (int)((blockIdx.x * blockDim.x + threadIdx.x) >> 6);
  int lane = threadIdx.x & 63;
  if (wid >= n) return;
  float2 v = ((const float2*)(x + (size_t)wid * 128))[lane];
  float s = v.x * v.x + v.y * v.y;
  #pragma unroll
  for (int off = 32; off; off >>= 1) s += __shfl_xor(s, off);
  float inv = 1.0f / (sqrtf(s) + 1e-12f);
  ((__half2*)(xn + (size_t)wid * 128))[lane] =
      __floats2half2_rn(v.x * inv, v.y * inv);
}

// ---------------------------------------------------------------------------
// 2) in-degree count
__global__ __launch_bounds__(256) void count_deg(
    const int* __restrict__ dst, int* __restrict__ deg, int e) {
  int i = blockIdx.x * blockDim.x + threadIdx.x;
  if (i < e) atomicAdd(&deg[dst[i]], 1);
}

// ---------------------------------------------------------------------------
// 3) exclusive scan: thread-local serial prefix + one block scan
__global__ void scan_excl(const int* __restrict__ deg, int* __restrict__ rowptr,
                          int* __restrict__ cursor, int n) {
  __shared__ int part[1024];
  int t = (int)threadIdx.x;
  int per = (n + 1023) / 1024;
  int b0 = t * per;
  int b1 = min(b0 + per, n);
  int s = 0;
  for (int i = b0; i < b1; ++i) s += deg[i];
  part[t] = s;
  __syncthreads();
  for (int off = 1; off < 1024; off <<= 1) {
    int v = (t >= off) ? part[t - off] : 0;
    __syncthreads();
    part[t] += v;
    __syncthreads();
  }
  int run = part[t] - s;
  for (int i = b0; i < b1; ++i) {
    rowptr[i] = run;
    cursor[i] = run;
    run += deg[i];
  }
  if (t == 1023) rowptr[n] = run;
}

// ---------------------------------------------------------------------------
// 4) CSR build: scatter ONLY the 2B src id (no gathers, minimal payload)
__global__ __launch_bounds__(256) void build_csr(
    const int* __restrict__ src, const int* __restrict__ dst,
    int* __restrict__ cursor, unsigned short* __restrict__ csr_src16, int e) {
  int i = blockIdx.x * blockDim.x + threadIdx.x;
  if (i < e) {
    int d = dst[i];
    int pos = atomicAdd(&cursor[d], 1);
    csr_src16[pos] = (unsigned short)src[i];
  }
}

// ---------------------------------------------------------------------------
// 5) edge weights, dst-ordered: one wave per dst node. dst row read ONCE,
// src rows gathered (4 edges in flight, 16 lanes each), packed (src|w16)
// written coalesced, denom reduced wave-locally (no atomics).
__global__ __launch_bounds__(256) void edge_weights(
    const __half* __restrict__ xn, const int* __restrict__ rowptr,
    const unsigned short* __restrict__ csr_src16,
    unsigned* __restrict__ csrp, float* __restrict__ denom, int n) {
  int wid  = (int)((blockIdx.x * blockDim.x + threadIdx.x) >> 6);
  int lane = threadIdx.x & 63;
  if (wid >= n) return;
  int grp = lane >> 4;       // edge slot 0..3
  int sub = lane & 15;       // 8-dim slice
  int beg = rowptr[wid], end = rowptr[wid + 1];
  int4 xdv = ((const int4*)(xn + (size_t)wid * 128))[sub];
  float wsum = 0.0f;

  for (int base = beg; base < end; base += 64) {
    int m = min(64, end - base);
    int sv = (lane < m) ? (int)csr_src16[base + lane] : 0;
    int iters = (m + 3) >> 2;
    #pragma unroll 2
    for (int q = 0; q < iters; ++q) {
      int ei = q * 4 + grp;
      int s = __shfl(sv, ei);
      int4 xsv = ((const int4*)(xn + (size_t)s * 128))[sub];
      float dp = dot8h(xsv, xdv);
      dp += __shfl_xor(dp, 1);
      dp += __shfl_xor(dp, 2);
      dp += __shfl_xor(dp, 4);
      dp += __shfl_xor(dp, 8);
      bool valid = ei < m;
      float w = valid ? __expf(dp * (1.0f / TAU)) : 0.0f;
      wsum += w;
      if (valid && sub == 0) {
        unsigned w16 = (unsigned)__half_as_ushort(__float2half_rn(w));
        csrp[base + ei] = (unsigned)s | (w16 << 16);
      }
    }
  }
  // wsum is uniform within each 16-lane group; combine the 4 groups
  wsum += __shfl_xor(wsum, 16);
  wsum += __shfl_xor(wsum, 32);
  if (lane == 0) denom[wid] = wsum;
}

// ---------------------------------------------------------------------------
// 6) dual GEMM: Y = fp16(H @ Wn) written as 32-channel PLANES
//    (plane p holds cols [32p,32p+32), row stride 32);
//    Z = fp16(H @ Wr + cn + cr) as full rows.
template <int DO>
__global__ __launch_bounds__(256) void gemm_dual(
    const float* __restrict__ H,
    const float* __restrict__ Wn, const float* __restrict__ Wr,
    const float* __restrict__ cn, const float* __restrict__ cr,
    __half* __restrict__ Y, __half* __restrict__ Z, int n) {
  __shared__ float hs[32][129];
  __shared__ float ws[128 * 64];
  const int t    = threadIdx.x;
  const int row0 = blockIdx.x * 32;

  for (int i = t; i < 1024; i += 256) {
    int r = i >> 5, c4 = i & 31;
    float4 v4 = make_float4(0.f, 0.f, 0.f, 0.f);
    if (row0 + r < n) v4 = ((const float4*)(H + (size_t)(row0 + r) * 128))[c4];
    hs[r][c4 * 4 + 0] = v4.x;
    hs[r][c4 * 4 + 1] = v4.y;
    hs[r][c4 * 4 + 2] = v4.z;
    hs[r][c4 * 4 + 3] = v4.w;
  }

  const int r_l = t >> 3;
  const int cg  = t & 7;
  const int row = row0 + r_l;

  for (int mat = 0; mat < 2; ++mat) {
    const float* W = mat ? Wr : Wn;
    for (int half = 0; half < DO / 64; ++half) {
      __syncthreads();
      for (int i = t; i < 128 * 16; i += 256) {
        int kk = i >> 4, c4 = i & 15;
        ((float4*)ws)[i] = ((const float4*)(W + (size_t)kk * DO + half * 64))[c4];
      }
      __syncthreads();

      float acc[8];
      #pragma unroll
      for (int q = 0; q < 8; ++q) acc[q] = 0.0f;

      #pragma unroll 8
      for (int k = 0; k < 128; ++k) {
        float hval = hs[r_l][k];
        const float4* wp = (const float4*)(ws + k * 64 + cg * 8);
        float4 w0 = wp[0], w1 = wp[1];
        acc[0] = fmaf(hval, w0.x, acc[0]);
        acc[1] = fmaf(hval, w0.y, acc[1]);
        acc[2] = fmaf(hval, w0.z, acc[2]);
        acc[3] = fmaf(hval, w0.w, acc[3]);
        acc[4] = fmaf(hval, w1.x, acc[4]);
        acc[5] = fmaf(hval, w1.y, acc[5]);
        acc[6] = fmaf(hval, w1.z, acc[6]);
        acc[7] = fmaf(hval, w1.w, acc[7]);
      }

      if (row < n) {
        int colbase = half * 64 + cg * 8;
        if (mat) {
          #pragma unroll
          for (int q = 0; q < 8; ++q) acc[q] += cn[colbase + q] + cr[colbase + q];
        }
        __half2 h0 = __floats2half2_rn(acc[0], acc[1]);
        __half2 h1 = __floats2half2_rn(acc[2], acc[3]);
        __half2 h2 = __floats2half2_rn(acc[4], acc[5]);
        __half2 h3 = __floats2half2_rn(acc[6], acc[7]);
        int4 pk;
        pk.x = *(int*)&h0; pk.y = *(int*)&h1;
        pk.z = *(int*)&h2; pk.w = *(int*)&h3;
        if (mat) {
          *((int4*)(Z + (size_t)row * DO + colbase)) = pk;
        } else {
          int pidx  = colbase >> 5;
          int incol = colbase & 31;
          *((int4*)(Y + ((size_t)pidx * n + row) * 32 + incol)) = pk;
        }
      }
    }
  }
}

// ---------------------------------------------------------------------------
// 7) aggregation pass over ONE 32-channel plane (3.2 MB working set -> L2):
//    out[d][c] = (sum_e w_e * Yp[src_e][c]) * inv_denom[d] + Z[d][c]  (+BN/ReLU)
//    8 edges in flight per wave (8 lanes/edge, int2 = 4 ch/lane).
template <bool DO_BN>
__global__ __launch_bounds__(256) void agg_pass(
    const __half* __restrict__ Yp, const __half* __restrict__ Zb,
    const int* __restrict__ rowptr, const unsigned* __restrict__ csrp,
    const float* __restrict__ denom,
    const float* __restrict__ g, const float* __restrict__ bb,
    const float* __restrict__ mm, const float* __restrict__ vv,
    float* __restrict__ out, int dofull, int choff, int n) {
  int wid  = (int)((blockIdx.x * blockDim.x + threadIdx.x) >> 6);
  int lane = threadIdx.x & 63;
  if (wid >= n) return;
  int grp = lane >> 3;     // edge slot 0..7
  int sub = lane & 7;      // channel quad 0..7 (4 ch each)
  int beg = rowptr[wid], end = rowptr[wid + 1];
  float inv = 1.0f / (denom[wid] + 1e-16f);

  float a0 = 0.f, a1 = 0.f, a2 = 0.f, a3 = 0.f;
  for (int base = beg; base < end; base += 64) {
    int m = min(64, end - base);
    unsigned pk = (lane < m) ? csrp[base + lane] : 0u;   // w=0 when inactive
    int iters = (m + 7) >> 3;
    #pragma unroll 4
    for (int q = 0; q < iters; ++q) {
      unsigned u = __shfl(pk, q * 8 + grp);
      int   s = (int)(u & 0xFFFFu);
      float w = __half2float(__ushort_as_half((unsigned short)(u >> 16)));
      int2 raw = ((const int2*)(Yp + (size_t)s * 32))[sub];
      float2 f0 = __half22float2(*(const __half2*)&raw.x);
      float2 f1 = __half22float2(*(const __half2*)&raw.y);
      a0 = fmaf(w, f0.x, a0);
      a1 = fmaf(w, f0.y, a1);
      a2 = fmaf(w, f1.x, a2);
      a3 = fmaf(w, f1.y, a3);
    }
  }
  #pragma unroll
  for (int off = 32; off >= 8; off >>= 1) {
    a0 += __shfl_xor(a0, off);
    a1 += __shfl_xor(a1, off);
    a2 += __shfl_xor(a2, off);
    a3 += __shfl_xor(a3, off);
  }

  if (lane < 8) {
    int c = choff + sub * 4;
    int2 zraw = *(const int2*)(Zb + (size_t)wid * dofull + c);
    float2 z0 = __half22float2(*(const __half2*)&zraw.x);
    float2 z1 = __half22float2(*(const __half2*)&zraw.y);
    float o0 = fmaf(a0, inv, z0.x);
    float o1 = fmaf(a1, inv, z0.y);
    float o2 = fmaf(a2, inv, z1.x);
    float o3 = fmaf(a3, inv, z1.y);
    if constexpr (DO_BN) {
      float s0 = g[c + 0] * rsqrtf(vv[c + 0] + BN_EPS);
      float s1 = g[c + 1] * rsqrtf(vv[c + 1] + BN_EPS);
      float s2 = g[c + 2] * rsqrtf(vv[c + 2] + BN_EPS);
      float s3 = g[c + 3] * rsqrtf(vv[c + 3] + BN_EPS);
      o0 = fmaxf(fmaf(o0 - mm[c + 0], s0, bb[c + 0]), 0.0f);
      o1 = fmaxf(fmaf(o1 - mm[c + 1], s1, bb[c + 1]), 0.0f);
      o2 = fmaxf(fmaf(o2 - mm[c + 2], s2, bb[c + 2]), 0.0f);
      o3 = fmaxf(fmaf(o3 - mm[c + 3], s3, bb[c + 3]), 0.0f);
    }
    *(float4*)(out + (size_t)wid * dofull + c) = make_float4(o0, o1, o2, o3);
  }
}

// ---------------------------------------------------------------------------
extern "C" void kernel_launch(void* const* d_in, const int* in_sizes, int n_in,
                              void* d_out, int out_size, void* d_ws, size_t ws_size,
                              hipStream_t stream) {
  const float* x   = (const float*)d_in[0];
  const int*   ei  = (const int*)d_in[1];
  const float* Wn0 = (const float*)d_in[2];
  const float* cn0 = (const float*)d_in[3];
  const float* Wr0 = (const float*)d_in[4];
  const float* cr0 = (const float*)d_in[5];
  const float* Wn1 = (const float*)d_in[6];
  const float* cn1 = (const float*)d_in[7];
  const float* Wr1 = (const float*)d_in[8];
  const float* cr1 = (const float*)d_in[9];
  const float* Wn2 = (const float*)d_in[10];
  const float* cn2 = (const float*)d_in[11];
  const float* Wr2 = (const float*)d_in[12];
  const float* cr2 = (const float*)d_in[13];
  const float* g0  = (const float*)d_in[14];
  const float* b0  = (const float*)d_in[15];
  const float* m0  = (const float*)d_in[16];
  const float* v0  = (const float*)d_in[17];
  const float* g1  = (const float*)d_in[18];
  const float* b1  = (const float*)d_in[19];
  const float* m1  = (const float*)d_in[20];
  const float* v1  = (const float*)d_in[21];

  const int* src = ei;
  const int* dst = ei + E_EDGES;

  char* p = (char*)d_ws;
  auto alloc = [&](size_t bytes) {
    char* r = p;
    p += (bytes + 255) & ~(size_t)255;
    return r;
  };
  __half*         P0      = (__half*)        alloc((size_t)N_NODES * 128 * 2); // xn -> Y planes
  __half*         P1      = (__half*)        alloc((size_t)N_NODES * 128 * 2); // Z rows
  int*            deg     = (int*)           alloc((size_t)N_NODES * 4);
  float*          denom   = (float*)         alloc((size_t)N_NODES * 4);
  int*            rowptr  = (int*)           alloc((size_t)(N_NODES + 1) * 4);
  int*            cursor  = (int*)           alloc((size_t)N_NODES * 4);
  unsigned short* csrs16  = (unsigned short*)alloc((size_t)E_EDGES * 2);
  unsigned*       csrp    = (unsigned*)      alloc((size_t)E_EDGES * 4);
  float*          A       = (float*)         alloc((size_t)N_NODES * 128 * 4); // H (f32)

  hipMemsetAsync(deg, 0, (size_t)N_NODES * 4, stream);

  const int node_grid = (N_NODES * 64 + 255) / 256;   // one wave per node

  xn_norm<<<node_grid, 256, 0, stream>>>(x, P0, N_NODES);
  count_deg<<<(E_EDGES + 255) / 256, 256, 0, stream>>>(dst, deg, E_EDGES);
  scan_excl<<<1, 1024, 0, stream>>>(deg, rowptr, cursor, N_NODES);
  build_csr<<<(E_EDGES + 255) / 256, 256, 0, stream>>>(src, dst, cursor, csrs16, E_EDGES);
  edge_weights<<<node_grid, 256, 0, stream>>>(P0, rowptr, csrs16, csrp, denom, N_NODES);

  const int gemm_grid = (N_NODES + 31) / 32;

  // layer 0: H = x, Y planes -> P0 (xn dead now), Z -> P1, out -> A
  gemm_dual<128><<<gemm_grid, 256, 0, stream>>>(x, Wn0, Wr0, cn0, cr0, P0, P1, N_NODES);
  for (int pass = 0; pass < 4; ++pass)
    agg_pass<true><<<node_grid, 256, 0, stream>>>(
        P0 + (size_t)pass * N_NODES * 32, P1, rowptr, csrp, denom,
        g0, b0, m0, v0, A, 128, pass * 32, N_NODES);

  // layer 1
  gemm_dual<128><<<gemm_grid, 256, 0, stream>>>(A, Wn1, Wr1, cn1, cr1, P0, P1, N_NODES);
  for (int pass = 0; pass < 4; ++pass)
    agg_pass<true><<<node_grid, 256, 0, stream>>>(
        P0 + (size_t)pass * N_NODES * 32, P1, rowptr, csrp, denom,
        g1, b1, m1, v1, A, 128, pass * 32, N_NODES);

  // layer 2 (64-wide, no BN, straight to d_out)
  gemm_dual<64><<<gemm_grid, 256, 0, stream>>>(A, Wn2, Wr2, cn2, cr2, P0, P1, N_NODES);
  for (int pass = 0; pass < 2; ++pass)
    agg_pass<false><<<node_grid, 256, 0, stream>>>(
        P0 + (size_t)pass * N_NODES * 32, P1, rowptr, csrp, denom,
        nullptr, nullptr, nullptr, nullptr, (float*)d_out, 64, pass * 32, N_NODES);
}